// Round 13
// baseline (290.830 us; speedup 1.0000x reference)
//
#include <hip/hip_runtime.h>

// SoftDTW: B=64, N=512, M=512, DIM=64, GAMMA=1.0, BANDWIDTH=0, BIG=1e10
constexpr int Bc   = 64;
constexpr int Nc   = 512;
constexpr int Mc   = 512;
constexpr int DIMc = 64;
constexpr float BIGc = 1e10f;
constexpr int CELLS = Nc * Mc;          // 1 MiB/batch compact diag-major D (prescaled)
constexpr float LOG2E = 1.442695041f;
constexpr float LN2   = 0.6931471806f;

// compact diag storage: cell (row n, col m), g=n+m, lives at dOffm(g) + n
__device__ __forceinline__ int dOffm(int g) {
    if (g < 512) return g * (g + 1) / 2;
    int e = g - 512;
    return 131328 + e * 511 - e * (e - 1) / 2 - (g - 511);
}

// lane l <- lane l-1 across the 64-lane wave; lane 0 <- old
__device__ __forceinline__ float dpp_shr1_f(float v, float old) {
    return __builtin_bit_cast(float, __builtin_amdgcn_update_dpp(
        __builtin_bit_cast(int, old), __builtin_bit_cast(int, v), 0x138, 0xF, 0xF, false));
}

// ---------------- Kernel A: D -> compact diag-major, 64x64 tiles + Ct staging ----
__global__ __launch_bounds__(256)
void compute_D_diag(const float* __restrict__ X, const float* __restrict__ Y,
                    float* __restrict__ Dc)
{
    const int b   = blockIdx.x;
    const int nt  = blockIdx.y;
    const int tid = threadIdx.x;
    const int ty  = tid >> 4, tx = tid & 15;

    __shared__ float Xs[DIMc][68];
    __shared__ float Ys[DIMc][68];
    __shared__ float Ct[64][66];

    const float* Xb = X + ((size_t)b * Nc + (size_t)nt * 64) * DIMc;
    const float* Yb = Y + (size_t)b * Mc * DIMc;
    float*       Db = Dc + (size_t)b * CELLS;
    const int n0 = nt * 64;

    {
        const float4* Xb4 = reinterpret_cast<const float4*>(Xb);
        for (int c4 = tid; c4 < 64 * DIMc / 4; c4 += 256) {
            float4 v = Xb4[c4];
            const int n = c4 >> 4, k0 = (c4 & 15) * 4;
            Xs[k0+0][n] = v.x; Xs[k0+1][n] = v.y; Xs[k0+2][n] = v.z; Xs[k0+3][n] = v.w;
        }
    }

    for (int mt = 0; mt < Mc / 64; ++mt) {
        __syncthreads();
        {
            const float4* Yb4 = reinterpret_cast<const float4*>(Yb + (size_t)mt * 64 * DIMc);
            for (int c4 = tid; c4 < 64 * DIMc / 4; c4 += 256) {
                float4 v = Yb4[c4];
                const int n = c4 >> 4, k0 = (c4 & 15) * 4;
                Ys[k0+0][n] = v.x; Ys[k0+1][n] = v.y; Ys[k0+2][n] = v.z; Ys[k0+3][n] = v.w;
            }
        }
        __syncthreads();

        float acc[4][4];
        #pragma unroll
        for (int r = 0; r < 4; ++r)
            #pragma unroll
            for (int cc = 0; cc < 4; ++cc) acc[r][cc] = 0.f;

        #pragma unroll 8
        for (int k = 0; k < DIMc; ++k) {
            float4 xv = *reinterpret_cast<const float4*>(&Xs[k][ty * 4]);
            float4 yv = *reinterpret_cast<const float4*>(&Ys[k][tx * 4]);
            float xr[4] = {xv.x, xv.y, xv.z, xv.w};
            float yr[4] = {yv.x, yv.y, yv.z, yv.w};
            #pragma unroll
            for (int r = 0; r < 4; ++r)
                #pragma unroll
                for (int cc = 0; cc < 4; ++cc) {
                    float d = xr[r] - yr[cc];
                    acc[r][cc] = fmaf(d, d, acc[r][cc]);
                }
        }

        #pragma unroll
        for (int r = 0; r < 4; ++r)
            #pragma unroll
            for (int cc = 0; cc < 4; ++cc)
                Ct[ty * 4 + r][tx * 4 + cc] = acc[r][cc] * LOG2E;
        __syncthreads();

        const int grp  = tid >> 6;
        const int lane = tid & 63;
        const int m0   = mt * 64;
        for (int d = grp; d < 127; d += 4) {
            const int tn_lo = max(0, d - 63);
            const int tn_hi = min(63, d);
            if (lane <= tn_hi - tn_lo) {
                const int tn = tn_lo + lane;
                const int dg = n0 + m0 + d;
                Db[dOffm(dg) + n0 + tn] = Ct[tn][d - tn];
            }
        }
    }
}

// ---------------- Kernel B: 4-wave systolic, TWO diagonals per chain-step --------
// Wave W owns rows 128W..128W+127; lane owns rA=128W+2*lane, rB=rA+1. Per pair
// (g, g+1): vA(g), vB(g) are LSE3s; vA(g+1), vB(g+1) are algebraically expanded
// 5-term LSEs over (g-1, g-2) state with D-only grouped coefficients c1/c2
// (computed off the serial chain). All four are INDEPENDENT given state ->
// chain advances 2 diagonals per LSE depth. NO masks: phantom cells (m<0,
// m>511, rows>L-1) stay ~BIG and flow only into phantoms; capture picks the
// real result cell. State: A1,A2,B1 (own), nb1,nb2 (neighbor row rB-1... rA-1
// vB-stream), na1,na2 (rA-2 vA-stream) via DPP / ring (B and A streams).
__global__ __launch_bounds__(256)
void softdtw_pair(const float* __restrict__ Dc, const int* __restrict__ lengths,
                  float* __restrict__ out)
{
    __shared__ float ringB[4][64];
    __shared__ float ringA[4][64];
    const int b    = blockIdx.x;
    const int t    = threadIdx.x;
    const int lane = t & 63;
    const int W    = __builtin_amdgcn_readfirstlane(t >> 6);   // 0..3
    const int L    = lengths[b];
    const int rA   = (W << 7) + (lane << 1);
    const int rB   = rA + 1;
    const int rAm1 = (rA == 0) ? 0 : rA - 1;    // clamp: lane0-W0's Du is dead
    const float* Dbat = Dc + (size_t)b * CELLS;

    if (t < 64) { ringB[0][t] = BIGc; ringA[0][t] = BIGc; }
    __syncthreads();

    const bool l0 = (lane == 0);
    const int gcapA = (rA == L - 1) ? (rA + 511) : -1;
    const int gcapB = (rB == L - 1) ? (rB + 511) : -1;
    const int qlL  = (L + 510) >> 5;
    const int q0   = 4 * W;
    const int ql   = min(4 * W + 19, qlL);
    const int cmax = qlL + 4;
    const int gEnd = 32 * (ql + 1);

    float A1=BIGc, A2=BIGc, B1=BIGc, nb1=BIGc, nb2=BIGc, na1=BIGc, na2=BIGc;
    float res = 0.f;
    if (W == 0 && l0) nb2 = 0.f;            // DP origin seed (cell (0,0) diag input)

    // D prefetch: 5 streams x 16 pair-slots (one 32-diag window)
    float Du_[16], Dax[16], Dbx[16], Day[16], Dby[16];
    int gR = 32 * q0, sbR = dOffm(32 * q0);
    #pragma unroll
    for (int p = 0; p < 16; ++p) {
        Du_[p] = Dbat[sbR + rAm1];
        Dax[p] = Dbat[sbR + rA];
        Dbx[p] = Dbat[sbR + rB];
        { int d1=(gR<512)?(gR+1):(1023-gR); sbR += d1-((gR>=511)?1:0); ++gR; }
        Day[p] = Dbat[sbR + rA];
        Dby[p] = Dbat[sbR + rB];
        { int d1=(gR<512)?(gR+1):(1023-gR); sbR += d1-((gR>=511)?1:0); ++gR; }
    }

    for (int c = 0; c < cmax; ++c) {
        const int q = c - W;
        if (q >= q0 && q <= ql) {
            const int g0 = q * 32;
            #pragma unroll
            for (int p = 0; p < 16; ++p) {
                const int g = g0 + 2 * p;
                // lane0 boundary pairs (uniform broadcast reads, off-chain)
                const float2 rBp = *reinterpret_cast<const float2*>(&ringB[W][g & 63]);
                const float2 rAp = *reinterpret_cast<const float2*>(&ringA[W][g & 63]);
                const float Du = Du_[p], DA = Dax[p], DB = Dbx[p];
                // grouped coefficients (off-chain; args <= 0 so no overflow)
                const float eDA = __builtin_amdgcn_exp2f(-DA);
                const float c1 = -__builtin_amdgcn_logf(
                                     __builtin_amdgcn_exp2f(-Du) + eDA + 1.f);
                const float c2 = -__builtin_amdgcn_logf(
                                     eDA + __builtin_amdgcn_exp2f(-DB) + 1.f);
                // vA(g) = DA + LSE3(nb1, A1, nb2)
                float mA = fminf(fminf(nb1, A1), nb2);
                float eA = __builtin_amdgcn_exp2f(mA-nb1)
                         + __builtin_amdgcn_exp2f(mA-A1)
                         + __builtin_amdgcn_exp2f(mA-nb2);
                float vAg = DA + (mA - __builtin_amdgcn_logf(eA));
                // vB(g) = DB + LSE3(A1, B1, A2)
                float mB = fminf(fminf(A1, B1), A2);
                float eB = __builtin_amdgcn_exp2f(mB-A1)
                         + __builtin_amdgcn_exp2f(mB-B1)
                         + __builtin_amdgcn_exp2f(mB-A2);
                float vBg = DB + (mB - __builtin_amdgcn_logf(eB));
                // vA(g+1) = Day + LSE5(na1+Du, na2+Du, A1+DA, nb2+DA, nb1+c1)
                float t1=na1+Du, t2=na2+Du, t3=A1+DA, t4=nb2+DA, t5=nb1+c1;
                float m5 = fminf(fminf(fminf(t1,t2), fminf(t3,t4)), t5);
                float e5 = __builtin_amdgcn_exp2f(m5-t1) + __builtin_amdgcn_exp2f(m5-t2)
                         + __builtin_amdgcn_exp2f(m5-t3) + __builtin_amdgcn_exp2f(m5-t4)
                         + __builtin_amdgcn_exp2f(m5-t5);
                float vAg1 = Day[p] + (m5 - __builtin_amdgcn_logf(e5));
                // vB(g+1) = Dby + LSE5(nb1+DA, nb2+DA, B1+DB, A2+DB, A1+c2)
                float u1=nb1+DA, u2=nb2+DA, u3=B1+DB, u4=A2+DB, u5=A1+c2;
                float n5 = fminf(fminf(fminf(u1,u2), fminf(u3,u4)), u5);
                float f5 = __builtin_amdgcn_exp2f(n5-u1) + __builtin_amdgcn_exp2f(n5-u2)
                         + __builtin_amdgcn_exp2f(n5-u3) + __builtin_amdgcn_exp2f(n5-u4)
                         + __builtin_amdgcn_exp2f(n5-u5);
                float vBg1 = Dby[p] + (n5 - __builtin_amdgcn_logf(f5));
                // result capture (cell (L-1, 511) at diag L+510)
                res = (g     == gcapA) ? vAg  : res;
                res = (g + 1 == gcapA) ? vAg1 : res;
                res = (g     == gcapB) ? vBg  : res;
                res = (g + 1 == gcapB) ? vBg1 : res;
                // ring export (lane63 -> wave W+1), packed b64
                if (W < 3 && lane == 63) {
                    *reinterpret_cast<float2*>(&ringB[W+1][g & 63]) = make_float2(vBg, vBg1);
                    *reinterpret_cast<float2*>(&ringA[W+1][g & 63]) = make_float2(vAg, vAg1);
                }
                // refill pair-slot p for window q+1 (guarded dummy past gEnd)
                {
                    bool dR1 = (gR < gEnd); int s1 = dR1 ? sbR : 0;
                    Du_[p]=Dbat[s1+rAm1]; Dax[p]=Dbat[s1+rA]; Dbx[p]=Dbat[s1+rB];
                    int d1=(gR<512)?(gR+1):(1023-gR); sbR += d1-((gR>=511)?1:0); ++gR;
                    bool dR2 = (gR < gEnd); int s2 = dR2 ? sbR : 0;
                    Day[p]=Dbat[s2+rA]; Dby[p]=Dbat[s2+rB];
                    int d2=(gR<512)?(gR+1):(1023-gR); sbR += d2-((gR>=511)?1:0); ++gR;
                }
                // neighbor/state update
                float shB0 = dpp_shr1_f(vBg,  BIGc);
                float shB1 = dpp_shr1_f(vBg1, BIGc);
                float shA0 = dpp_shr1_f(vAg,  BIGc);
                float shA1 = dpp_shr1_f(vAg1, BIGc);
                A2 = vAg; A1 = vAg1; B1 = vBg1;
                nb2 = l0 ? rBp.x : shB0;  nb1 = l0 ? rBp.y : shB1;
                na2 = l0 ? rAp.x : shA0;  na1 = l0 ? rAp.y : shA1;
            }
        } else if (W > 0 && q == q0 - 1) {
            // preload: slots 62/63 of previous parity = upstream values at
            // g = 128W-2, 128W-1 (vB stream) and same for vA stream
            nb1 = l0 ? ringB[W][63] : nb1;
            nb2 = l0 ? ringB[W][62] : nb2;
            na1 = l0 ? ringA[W][63] : na1;
            na2 = l0 ? ringA[W][62] : na2;
        }
        asm volatile("s_waitcnt lgkmcnt(0)" ::: "memory");  // ring writes visible
        __builtin_amdgcn_s_barrier();                       // no vmcnt drain
        asm volatile("" ::: "memory");
    }

    if (rA == L - 1 || rB == L - 1) out[b] = res * LN2;
}

// ---------------- Fallback (no workspace): fused on-the-fly D --------------------
__global__ __launch_bounds__(512)
void softdtw_fused(const float* __restrict__ X, const float* __restrict__ Y,
                   const int* __restrict__ lengths, float* __restrict__ out)
{
    const int b = blockIdx.x;
    const int t = threadIdx.x;
    const int i = t + 1;
    const int L = lengths[b];

    __shared__ float diag[3][Nc + 1];
    for (int c = t; c <= Nc; c += 512) {
        diag[0][c] = (c == 0) ? 0.f : BIGc;
        diag[1][c] = BIGc;
    }
    float xr[DIMc];
    const float* Xrow = X + ((size_t)b * Nc + t) * DIMc;
    #pragma unroll
    for (int d = 0; d < DIMc; d += 4) {
        float4 v = *reinterpret_cast<const float4*>(Xrow + d);
        xr[d] = v.x; xr[d+1] = v.y; xr[d+2] = v.z; xr[d+3] = v.w;
    }
    const float* Yb = Y + (size_t)b * Mc * DIMc;
    __syncthreads();

    float result = BIGc;
    int cur = 2, p1 = 1, p2 = 0;
    for (int k = 2; k <= Nc + Mc; ++k) {
        const int j = k - i;
        const bool valid = (j >= 1) && (j <= Mc) && (i <= L);
        float Dval = 0.f;
        if (valid) {
            const float* Yrow = Yb + (size_t)(j - 1) * DIMc;
            float s = 0.f;
            #pragma unroll
            for (int d = 0; d < DIMc; d += 4) {
                float4 v = *reinterpret_cast<const float4*>(Yrow + d);
                float d0 = xr[d] - v.x, d1 = xr[d+1] - v.y;
                float d2 = xr[d+2] - v.z, d3 = xr[d+3] - v.w;
                s = fmaf(d0,d0,s); s = fmaf(d1,d1,s); s = fmaf(d2,d2,s); s = fmaf(d3,d3,s);
            }
            Dval = s;
        }
        const float a2 = diag[p2][i-1], a1 = diag[p1][i-1], a0 = diag[p1][i];
        const float mn = fminf(a2, fminf(a1, a0));
        const float sm = mn - __logf(__expf(mn-a2) + __expf(mn-a1) + __expf(mn-a0));
        const float val = valid ? (Dval + sm) : BIGc;
        diag[cur][i] = val;
        if (t == 0) diag[cur][0] = BIGc;
        if (k == L + Mc && i == L) result = val;
        __syncthreads();
        const int tmp = p2; p2 = p1; p1 = cur; cur = tmp;
    }
    if (i == L) out[b] = result;
}

extern "C" void kernel_launch(void* const* d_in, const int* in_sizes, int n_in,
                              void* d_out, int out_size, void* d_ws, size_t ws_size,
                              hipStream_t stream) {
    const float* X = (const float*)d_in[0];
    const float* Y = (const float*)d_in[1];
    const int* lengths = (const int*)d_in[2];
    float* out = (float*)d_out;

    const size_t need = (size_t)Bc * CELLS * sizeof(float);   // 64 MiB
    if (ws_size >= need) {
        float* Dc = (float*)d_ws;
        compute_D_diag<<<dim3(Bc, Nc / 64), 256, 0, stream>>>(X, Y, Dc);
        softdtw_pair<<<Bc, 256, 0, stream>>>(Dc, lengths, out);
    } else {
        softdtw_fused<<<Bc, 512, 0, stream>>>(X, Y, lengths, out);
    }
}

// Round 14
// 237.127 us; speedup vs baseline: 1.2265x; 1.2265x over previous
//
#include <hip/hip_runtime.h>

// SoftDTW: B=64, N=512, M=512, DIM=64, GAMMA=1.0, BANDWIDTH=0, BIG=1e10
constexpr int Bc   = 64;
constexpr int Nc   = 512;
constexpr int Mc   = 512;
constexpr int DIMc = 64;
constexpr float BIGc = 1e10f;
constexpr int CELLS = Nc * Mc;          // per-batch compact diag-major D (bf16, prescaled)
constexpr float LOG2E = 1.442695041f;
constexpr float LN2   = 0.6931471806f;

struct TrueC  { static constexpr bool value = true;  };
struct FalseC { static constexpr bool value = false; };

// compact diag storage: cell (row n, col m), g=n+m, lives at dOffm(g) + n
__device__ __forceinline__ int diag_off(int g) {
    if (g < Mc) return g * (g + 1) / 2;
    int e = g - Mc;
    return Mc * (Mc + 1) / 2 + e * (Nc - 1) - e * (e - 1) / 2;
}
__device__ __forceinline__ int diag_nmin(int g) {
    return (g > Mc - 1) ? (g - (Mc - 1)) : 0;
}
__device__ __forceinline__ int dOffm(int g) {
    if (g < 512) return g * (g + 1) / 2;
    int e = g - 512;
    return 131328 + e * 511 - e * (e - 1) / 2 - (g - 511);
}

// float -> bf16 bits, round-to-nearest-even (values are finite positive)
__device__ __forceinline__ unsigned short f2bf_rne(float f) {
    unsigned u = __builtin_bit_cast(unsigned, f);
    u += 0x7FFFu + ((u >> 16) & 1u);
    return (unsigned short)(u >> 16);
}

// lane l <- lane l-1 across the 64-lane wave; lane 0 <- old
__device__ __forceinline__ float dpp_shr1_f(float v, float old) {
    return __builtin_bit_cast(float, __builtin_amdgcn_update_dpp(
        __builtin_bit_cast(int, old), __builtin_bit_cast(int, v), 0x138, 0xF, 0xF, false));
}
__device__ __forceinline__ float f4c(const float4 v, int c) {
    switch (c & 3) { case 0: return v.x; case 1: return v.y;
                     case 2: return v.z; default: return v.w; }
}
__device__ __forceinline__ void f4set(float4& d, int c, float v) {
    switch (c & 3) { case 0: d.x = v; break; case 1: d.y = v; break;
                     case 2: d.z = v; break; default: d.w = v; }
}

// ---------------- Kernel A: D -> compact diag-major bf16, 64x64 tiles + Ct -------
__global__ __launch_bounds__(256)
void compute_D_diag(const float* __restrict__ X, const float* __restrict__ Y,
                    unsigned short* __restrict__ Dc)
{
    const int b   = blockIdx.x;
    const int nt  = blockIdx.y;
    const int tid = threadIdx.x;
    const int ty  = tid >> 4, tx = tid & 15;

    __shared__ float Xs[DIMc][68];
    __shared__ float Ys[DIMc][68];
    __shared__ float Ct[64][66];

    const float* Xb = X + ((size_t)b * Nc + (size_t)nt * 64) * DIMc;
    const float* Yb = Y + (size_t)b * Mc * DIMc;
    unsigned short* Db = Dc + (size_t)b * CELLS;
    const int n0 = nt * 64;

    {
        const float4* Xb4 = reinterpret_cast<const float4*>(Xb);
        for (int c4 = tid; c4 < 64 * DIMc / 4; c4 += 256) {
            float4 v = Xb4[c4];
            const int n = c4 >> 4, k0 = (c4 & 15) * 4;
            Xs[k0+0][n] = v.x; Xs[k0+1][n] = v.y; Xs[k0+2][n] = v.z; Xs[k0+3][n] = v.w;
        }
    }

    for (int mt = 0; mt < Mc / 64; ++mt) {
        __syncthreads();
        {
            const float4* Yb4 = reinterpret_cast<const float4*>(Yb + (size_t)mt * 64 * DIMc);
            for (int c4 = tid; c4 < 64 * DIMc / 4; c4 += 256) {
                float4 v = Yb4[c4];
                const int n = c4 >> 4, k0 = (c4 & 15) * 4;
                Ys[k0+0][n] = v.x; Ys[k0+1][n] = v.y; Ys[k0+2][n] = v.z; Ys[k0+3][n] = v.w;
            }
        }
        __syncthreads();

        float acc[4][4];
        #pragma unroll
        for (int r = 0; r < 4; ++r)
            #pragma unroll
            for (int cc = 0; cc < 4; ++cc) acc[r][cc] = 0.f;

        #pragma unroll 8
        for (int k = 0; k < DIMc; ++k) {
            float4 xv = *reinterpret_cast<const float4*>(&Xs[k][ty * 4]);
            float4 yv = *reinterpret_cast<const float4*>(&Ys[k][tx * 4]);
            float xr[4] = {xv.x, xv.y, xv.z, xv.w};
            float yr[4] = {yv.x, yv.y, yv.z, yv.w};
            #pragma unroll
            for (int r = 0; r < 4; ++r)
                #pragma unroll
                for (int cc = 0; cc < 4; ++cc) {
                    float d = xr[r] - yr[cc];
                    acc[r][cc] = fmaf(d, d, acc[r][cc]);
                }
        }

        #pragma unroll
        for (int r = 0; r < 4; ++r)
            #pragma unroll
            for (int cc = 0; cc < 4; ++cc)
                Ct[ty * 4 + r][tx * 4 + cc] = acc[r][cc] * LOG2E;
        __syncthreads();

        const int grp  = tid >> 6;
        const int lane = tid & 63;
        const int m0   = mt * 64;
        for (int d = grp; d < 127; d += 4) {
            const int tn_lo = max(0, d - 63);
            const int tn_hi = min(63, d);
            if (lane <= tn_hi - tn_lo) {
                const int tn = tn_lo + lane;
                const int dg = n0 + m0 + d;
                Db[dOffm(dg) + n0 + tn] = f2bf_rne(Ct[tn][d - tn]);
            }
        }
    }
}

// ---------------- Kernel B: 8-wave systolic, CHUNK=16, bf16 diag-direct loads ----
// Wave W owns rows r = 64W..64W+63 (lane = row). Window q = diags [16q,16q+16).
// Schedule: wave W does window q at c = q+W; q0=4W, ql=min(4W+35,qlL),
// qlL=(L+510)>>4, cmax=qlL+8. Ring[W][64] = 4 windows of row-(64W-1) values;
// slot s consumed at END of step s (sets nb1 for step s+1), preload covers the
// first-window entry (slots 62/63 = g=64W-2, 64W-1). D loads: scalar SALU base
// sb + constant r, raw u16 kept in Dwin, shifted to f32 at window start
// (off-chain). Fast windows q in [4W+4, 4W+31] (all cells interior; capture
// provably outside when rowsOK) run the mask-free body.
__global__ __launch_bounds__(512)
void softdtw_sys16(const unsigned short* __restrict__ Dch,
                   const int* __restrict__ lengths, float* __restrict__ out)
{
    __shared__ float ring[8][64];
    const int b    = blockIdx.x;
    const int t    = threadIdx.x;
    const int lane = t & 63;
    const int W    = __builtin_amdgcn_readfirstlane(t >> 6);   // scalar 0..7
    const int L    = lengths[b];
    const int r    = (W << 6) + lane;       // 0-based row
    const unsigned short* Dbat = Dch + (size_t)b * CELLS;

    if (t < 64) ring[0][t] = BIGc;          // ring[0] has no writer
    __syncthreads();

    const bool l0   = (lane == 0);
    const bool iok  = (r <= L - 1);
    const int  gcap = (r == L - 1) ? (L + 510) : -1;   // diag of result cell
    const int  qlL  = (L + 510) >> 4;
    const bool rowsOK = ((W << 6) + 64) <= L;
    const int  q0 = 4 * W;
    const int  ql = min(4 * W + 35, qlL);
    const int  cmax = qlL + 8;

    float own = BIGc, nb1 = BIGc, nb2 = BIGc, res = 0.f;
    if (W == 0 && l0) nb2 = 0.f;            // DP origin seed for cell (0,0)

    // prologue: raw u16 loads for window q0 (g = 64W+s, rising region)
    unsigned Dwin[16];
    {
        int sb = dOffm(q0 * 16);
        int gg = q0 * 16;
        #pragma unroll
        for (int s = 0; s < 16; ++s) {
            Dwin[s] = Dbat[sb + r];
            int d1 = (gg < 512) ? (gg + 1) : (1023 - gg);
            sb += d1 - ((gg >= 511) ? 1 : 0);
            ++gg;
        }
    }

    for (int c = 0; c < cmax; ++c) {
        const int q = c - W;
        if (q >= q0 && q <= ql) {
            const int g0 = q * 16;
            const int rbase = g0 & 63;

            // bf16 -> f32 for current window (off-chain, after implicit vmcnt)
            float Df[16];
            #pragma unroll
            for (int s = 0; s < 16; ++s)
                Df[s] = __builtin_bit_cast(float, Dwin[s] << 16);

            // ring window in (uniform broadcast b128 reads, off the chain)
            float4 rv[4];
            {
                const float4* rp = reinterpret_cast<const float4*>(&ring[W][rbase]);
                #pragma unroll
                for (int u = 0; u < 4; ++u) rv[u] = rp[u];
            }

            // scalar base chain for next-window refills
            const bool doNext = (q + 1 <= ql);
            int gN  = doNext ? (g0 + 16) : 0;
            int sbN = dOffm(gN);

            float4 expv[4];
            const bool fastC = rowsOK && q >= q0 + 4 && q <= q0 + 31 && q != qlL;

            auto body = [&](auto FASTC) {
                constexpr bool FAST = decltype(FASTC)::value;
                #pragma unroll
                for (int s = 0; s < 16; ++s) {
                    const int g = g0 + s;
                    const float mn = fminf(nb2, fminf(nb1, own));
                    const float e  = __builtin_amdgcn_exp2f(mn - nb2)
                                   + __builtin_amdgcn_exp2f(mn - nb1)
                                   + __builtin_amdgcn_exp2f(mn - own);
                    const float sm = mn - __builtin_amdgcn_logf(e);   // log2
                    float v = Df[s] + sm;
                    if (!FAST) {
                        const bool jok = (unsigned)(g - r) < (unsigned)Mc;
                        v = (jok && iok) ? v : BIGc;
                        res = (g == gcap) ? v : res;   // capture (always slow window)
                    }
                    // refill slot s from window q+1 (scalar base + constant r)
                    Dwin[s] = Dbat[sbN + r];
                    {
                        int d1 = (gN < 512) ? (gN + 1) : (1023 - gN);
                        sbN += d1 - ((gN >= 511) ? 1 : 0);
                        ++gN;
                    }
                    f4set(expv[s >> 2], s, v);
                    const float sh = dpp_shr1_f(v, BIGc);
                    nb2 = nb1;
                    nb1 = l0 ? f4c(rv[s >> 2], s) : sh;   // slot s -> nb1 for g+1
                    own = v;
                }
            };
            if (fastC) body(TrueC{}); else body(FalseC{});

            // ring export: 4x b128 from packed regs (lane 63 only)
            if (W < 7 && lane == 63) {
                float* re = &ring[W + 1][rbase];
                #pragma unroll
                for (int u = 0; u < 4; ++u)
                    reinterpret_cast<float4*>(re)[u] = expv[u];
            }
        } else if (W > 0 && q == q0 - 1) {
            // preload: ring slots 62/63 hold v(64W-1, 64W-2) and v(64W-1, 64W-1)
            nb1 = l0 ? ring[W][63] : nb1;
            nb2 = l0 ? ring[W][62] : nb2;
        }
        asm volatile("s_waitcnt lgkmcnt(0)" ::: "memory");  // ring writes visible
        __builtin_amdgcn_s_barrier();                       // no vmcnt drain
        asm volatile("" ::: "memory");
    }

    if (r == L - 1) out[b] = res * LN2;
}

// ---------------- Fallback (no workspace): fused on-the-fly D --------------------
__global__ __launch_bounds__(512)
void softdtw_fused(const float* __restrict__ X, const float* __restrict__ Y,
                   const int* __restrict__ lengths, float* __restrict__ out)
{
    const int b = blockIdx.x;
    const int t = threadIdx.x;
    const int i = t + 1;
    const int L = lengths[b];

    __shared__ float diag[3][Nc + 1];
    for (int c = t; c <= Nc; c += 512) {
        diag[0][c] = (c == 0) ? 0.f : BIGc;
        diag[1][c] = BIGc;
    }
    float xr[DIMc];
    const float* Xrow = X + ((size_t)b * Nc + t) * DIMc;
    #pragma unroll
    for (int d = 0; d < DIMc; d += 4) {
        float4 v = *reinterpret_cast<const float4*>(Xrow + d);
        xr[d] = v.x; xr[d+1] = v.y; xr[d+2] = v.z; xr[d+3] = v.w;
    }
    const float* Yb = Y + (size_t)b * Mc * DIMc;
    __syncthreads();

    float result = BIGc;
    int cur = 2, p1 = 1, p2 = 0;
    for (int k = 2; k <= Nc + Mc; ++k) {
        const int j = k - i;
        const bool valid = (j >= 1) && (j <= Mc) && (i <= L);
        float Dval = 0.f;
        if (valid) {
            const float* Yrow = Yb + (size_t)(j - 1) * DIMc;
            float s = 0.f;
            #pragma unroll
            for (int d = 0; d < DIMc; d += 4) {
                float4 v = *reinterpret_cast<const float4*>(Yrow + d);
                float d0 = xr[d] - v.x, d1 = xr[d+1] - v.y;
                float d2 = xr[d+2] - v.z, d3 = xr[d+3] - v.w;
                s = fmaf(d0,d0,s); s = fmaf(d1,d1,s); s = fmaf(d2,d2,s); s = fmaf(d3,d3,s);
            }
            Dval = s;
        }
        const float a2 = diag[p2][i-1], a1 = diag[p1][i-1], a0 = diag[p1][i];
        const float mn = fminf(a2, fminf(a1, a0));
        const float sm = mn - __logf(__expf(mn-a2) + __expf(mn-a1) + __expf(mn-a0));
        const float val = valid ? (Dval + sm) : BIGc;
        diag[cur][i] = val;
        if (t == 0) diag[cur][0] = BIGc;
        if (k == L + Mc && i == L) result = val;
        __syncthreads();
        const int tmp = p2; p2 = p1; p1 = cur; cur = tmp;
    }
    if (i == L) out[b] = result;
}

extern "C" void kernel_launch(void* const* d_in, const int* in_sizes, int n_in,
                              void* d_out, int out_size, void* d_ws, size_t ws_size,
                              hipStream_t stream) {
    const float* X = (const float*)d_in[0];
    const float* Y = (const float*)d_in[1];
    const int* lengths = (const int*)d_in[2];
    float* out = (float*)d_out;

    const size_t need = (size_t)Bc * CELLS * sizeof(unsigned short);  // 32 MiB
    if (ws_size >= need) {
        unsigned short* Dc = (unsigned short*)d_ws;
        compute_D_diag<<<dim3(Bc, Nc / 64), 256, 0, stream>>>(X, Y, Dc);
        softdtw_sys16<<<Bc, 512, 0, stream>>>(Dc, lengths, out);
    } else {
        softdtw_fused<<<Bc, 512, 0, stream>>>(X, Y, lengths, out);
    }
}

// Round 15
// 183.588 us; speedup vs baseline: 1.5841x; 1.2916x over previous
//
#include <hip/hip_runtime.h>

// SoftDTW: B=64, N=512, M=512, DIM=64, GAMMA=1.0, BANDWIDTH=0, BIG=1e10
constexpr int Bc   = 64;
constexpr int Nc   = 512;
constexpr int Mc   = 512;
constexpr int DIMc = 64;
constexpr float BIGc = 1e10f;
constexpr int CELLS = Nc * Mc;          // per-batch compact diag-major D (bf16, prescaled)
constexpr float LOG2E = 1.442695041f;
constexpr float LN2   = 0.6931471806f;

struct TrueC  { static constexpr bool value = true;  };
struct FalseC { static constexpr bool value = false; };

typedef __attribute__((ext_vector_type(8))) short short8v;   // bf16x8 MFMA frag
typedef __attribute__((ext_vector_type(4))) float f32x4;     // MFMA accumulator

// compact diag storage: cell (row n, col m), g=n+m, lives at dOffm(g) + n
__device__ __forceinline__ int diag_off(int g) {
    if (g < Mc) return g * (g + 1) / 2;
    int e = g - Mc;
    return Mc * (Mc + 1) / 2 + e * (Nc - 1) - e * (e - 1) / 2;
}
__device__ __forceinline__ int diag_nmin(int g) {
    return (g > Mc - 1) ? (g - (Mc - 1)) : 0;
}
__device__ __forceinline__ int dOffm(int g) {
    if (g < 512) return g * (g + 1) / 2;
    int e = g - 512;
    return 131328 + e * 511 - e * (e - 1) / 2 - (g - 511);
}

// float -> bf16 bits, round-to-nearest-even
__device__ __forceinline__ unsigned short f2bf_rne(float f) {
    unsigned u = __builtin_bit_cast(unsigned, f);
    u += 0x7FFFu + ((u >> 16) & 1u);
    return (unsigned short)(u >> 16);
}
__device__ __forceinline__ float bf2f(unsigned short h) {
    return __builtin_bit_cast(float, (unsigned)h << 16);
}

// lane l <- lane l-1 across the 64-lane wave; lane 0 <- old
__device__ __forceinline__ float dpp_shr1_f(float v, float old) {
    return __builtin_bit_cast(float, __builtin_amdgcn_update_dpp(
        __builtin_bit_cast(int, old), __builtin_bit_cast(int, v), 0x138, 0xF, 0xF, false));
}
__device__ __forceinline__ float f4c(const float4 v, int c) {
    switch (c & 3) { case 0: return v.x; case 1: return v.y;
                     case 2: return v.z; default: return v.w; }
}
__device__ __forceinline__ void f4set(float4& d, int c, float v) {
    switch (c & 3) { case 0: d.x = v; break; case 1: d.y = v; break;
                     case 2: d.z = v; break; default: d.w = v; }
}

// ---------------- Kernel A (MFMA): D = (|x|^2+|y|^2-2*X.Y^T)*log2e -> diag bf16 --
// Block = 256 thr (4 waves, 2x2 wave grid), 128x128 output tile. X/Y tiles
// staged once as bf16 in LDS (stride 72: 2-way banks on frag reads). S = X.Y^T
// via mfma_f32_16x16x32_bf16: A-frag = X row (lane&15), 8 contig k at
// (lane>>4)*8; B-frag = Y row (lane&15) same k (C=A.B^T, both row-major);
// C/D: col=lane&15, row=(lane>>4)*4+reg. Epilogue fuses norms, scales, packs
// bf16 into Ct, then 255-diag coalesced scatter to compact diag-major.
__global__ __launch_bounds__(256)
void compute_D_mfma(const float* __restrict__ X, const float* __restrict__ Y,
                    unsigned short* __restrict__ Dc)
{
    __shared__ unsigned short Xs[128 * 72];
    __shared__ unsigned short Ys[128 * 72];
    __shared__ unsigned short Ct[128 * 132];
    __shared__ float xn2[128], ym2[128];

    const int b   = blockIdx.x;
    const int nt  = blockIdx.y >> 2;
    const int mt_ = blockIdx.y & 3;
    const int n0  = nt * 128, m0 = mt_ * 128;
    const int tid = threadIdx.x;

    const float* Xb = X + ((size_t)b * Nc + n0) * DIMc;
    const float* Yb = Y + ((size_t)b * Mc + m0) * DIMc;
    unsigned short* Db = Dc + (size_t)b * CELLS;

    // stage X,Y tiles (128x64 f32 -> bf16 LDS), coalesced float4
    {
        const float4* Xb4 = reinterpret_cast<const float4*>(Xb);
        const float4* Yb4 = reinterpret_cast<const float4*>(Yb);
        #pragma unroll
        for (int it = 0; it < 8; ++it) {
            const int c4 = tid + it * 256;             // 0..2047
            const int row = c4 >> 4, k4 = (c4 & 15) * 4;
            float4 xv = Xb4[c4];
            float4 yv = Yb4[c4];
            ushort4 xs = make_ushort4(f2bf_rne(xv.x), f2bf_rne(xv.y),
                                      f2bf_rne(xv.z), f2bf_rne(xv.w));
            ushort4 ys = make_ushort4(f2bf_rne(yv.x), f2bf_rne(yv.y),
                                      f2bf_rne(yv.z), f2bf_rne(yv.w));
            *reinterpret_cast<ushort4*>(&Xs[row * 72 + k4]) = xs;
            *reinterpret_cast<ushort4*>(&Ys[row * 72 + k4]) = ys;
        }
    }
    __syncthreads();

    // row norms from the bf16 values (consistent with mfma inputs)
    {
        const int rr = tid & 127;
        const unsigned short* src = (tid < 128) ? Xs : Ys;
        float s = 0.f;
        #pragma unroll
        for (int kk = 0; kk < 64; ++kk) {
            float v = bf2f(src[rr * 72 + kk]);
            s = fmaf(v, v, s);
        }
        if (tid < 128) xn2[rr] = s; else ym2[rr] = s;
    }
    __syncthreads();

    // MFMA: wave (wr,wc) computes 64x64 sub-tile as 4x4 fragments
    const int w    = __builtin_amdgcn_readfirstlane(tid >> 6);
    const int lane = tid & 63;
    const int wr = w >> 1, wc = w & 1;
    const int lo = lane & 15, hi = lane >> 4;

    f32x4 acc[4][4];
    #pragma unroll
    for (int ri = 0; ri < 4; ++ri)
        #pragma unroll
        for (int ci = 0; ci < 4; ++ci) acc[ri][ci] = f32x4{0.f, 0.f, 0.f, 0.f};

    #pragma unroll
    for (int ks = 0; ks < 2; ++ks) {
        short8v a[4], bf[4];
        const int kb = ks * 32 + hi * 8;
        #pragma unroll
        for (int ri = 0; ri < 4; ++ri)
            a[ri] = *reinterpret_cast<const short8v*>(
                        &Xs[(wr * 64 + ri * 16 + lo) * 72 + kb]);
        #pragma unroll
        for (int ci = 0; ci < 4; ++ci)
            bf[ci] = *reinterpret_cast<const short8v*>(
                        &Ys[(wc * 64 + ci * 16 + lo) * 72 + kb]);
        #pragma unroll
        for (int ri = 0; ri < 4; ++ri)
            #pragma unroll
            for (int ci = 0; ci < 4; ++ci)
                acc[ri][ci] = __builtin_amdgcn_mfma_f32_16x16x32_bf16(
                                  a[ri], bf[ci], acc[ri][ci], 0, 0, 0);
    }

    // epilogue: D = (xn2 + ym2 - 2S)*log2e -> bf16 -> Ct
    #pragma unroll
    for (int ri = 0; ri < 4; ++ri)
        #pragma unroll
        for (int ci = 0; ci < 4; ++ci)
            #pragma unroll
            for (int rg = 0; rg < 4; ++rg) {
                const int row = wr * 64 + ri * 16 + hi * 4 + rg;
                const int col = wc * 64 + ci * 16 + lo;
                float val = fmaf(-2.f, acc[ri][ci][rg], xn2[row] + ym2[col]) * LOG2E;
                Ct[row * 132 + col] = f2bf_rne(val);
            }
    __syncthreads();

    // 255 tile-diagonals -> contiguous global segments (coalesced u16)
    const int grp = tid >> 6;
    const int g00 = n0 + m0;
    for (int d = grp; d < 255; d += 4) {
        const int tn_lo = max(0, d - 127);
        const int tn_hi = min(127, d);
        const int dg    = g00 + d;
        const int base  = dOffm(dg) + n0;
        for (int o = lane; o <= tn_hi - tn_lo; o += 64) {
            const int tn = tn_lo + o;
            Db[base + tn] = Ct[tn * 132 + (d - tn)];
        }
    }
}

// ---------------- Kernel B: 8-wave systolic, CHUNK=16, bf16 diag-direct loads ----
// (unchanged from round 14 — correct, 146 us)
__global__ __launch_bounds__(512)
void softdtw_sys16(const unsigned short* __restrict__ Dch,
                   const int* __restrict__ lengths, float* __restrict__ out)
{
    __shared__ float ring[8][64];
    const int b    = blockIdx.x;
    const int t    = threadIdx.x;
    const int lane = t & 63;
    const int W    = __builtin_amdgcn_readfirstlane(t >> 6);   // scalar 0..7
    const int L    = lengths[b];
    const int r    = (W << 6) + lane;       // 0-based row
    const unsigned short* Dbat = Dch + (size_t)b * CELLS;

    if (t < 64) ring[0][t] = BIGc;          // ring[0] has no writer
    __syncthreads();

    const bool l0   = (lane == 0);
    const bool iok  = (r <= L - 1);
    const int  gcap = (r == L - 1) ? (L + 510) : -1;   // diag of result cell
    const int  qlL  = (L + 510) >> 4;
    const bool rowsOK = ((W << 6) + 64) <= L;
    const int  q0 = 4 * W;
    const int  ql = min(4 * W + 35, qlL);
    const int  cmax = qlL + 8;

    float own = BIGc, nb1 = BIGc, nb2 = BIGc, res = 0.f;
    if (W == 0 && l0) nb2 = 0.f;            // DP origin seed for cell (0,0)

    // prologue: raw u16 loads for window q0 (g = 64W+s, rising region)
    unsigned Dwin[16];
    {
        int sb = dOffm(q0 * 16);
        int gg = q0 * 16;
        #pragma unroll
        for (int s = 0; s < 16; ++s) {
            Dwin[s] = Dbat[sb + r];
            int d1 = (gg < 512) ? (gg + 1) : (1023 - gg);
            sb += d1 - ((gg >= 511) ? 1 : 0);
            ++gg;
        }
    }

    for (int c = 0; c < cmax; ++c) {
        const int q = c - W;
        if (q >= q0 && q <= ql) {
            const int g0 = q * 16;
            const int rbase = g0 & 63;

            // bf16 -> f32 for current window (off-chain, after implicit vmcnt)
            float Df[16];
            #pragma unroll
            for (int s = 0; s < 16; ++s)
                Df[s] = __builtin_bit_cast(float, Dwin[s] << 16);

            // ring window in (uniform broadcast b128 reads, off the chain)
            float4 rv[4];
            {
                const float4* rp = reinterpret_cast<const float4*>(&ring[W][rbase]);
                #pragma unroll
                for (int u = 0; u < 4; ++u) rv[u] = rp[u];
            }

            // scalar base chain for next-window refills
            const bool doNext = (q + 1 <= ql);
            int gN  = doNext ? (g0 + 16) : 0;
            int sbN = dOffm(gN);

            float4 expv[4];
            const bool fastC = rowsOK && q >= q0 + 4 && q <= q0 + 31 && q != qlL;

            auto body = [&](auto FASTC) {
                constexpr bool FAST = decltype(FASTC)::value;
                #pragma unroll
                for (int s = 0; s < 16; ++s) {
                    const int g = g0 + s;
                    const float mn = fminf(nb2, fminf(nb1, own));
                    const float e  = __builtin_amdgcn_exp2f(mn - nb2)
                                   + __builtin_amdgcn_exp2f(mn - nb1)
                                   + __builtin_amdgcn_exp2f(mn - own);
                    const float sm = mn - __builtin_amdgcn_logf(e);   // log2
                    float v = Df[s] + sm;
                    if (!FAST) {
                        const bool jok = (unsigned)(g - r) < (unsigned)Mc;
                        v = (jok && iok) ? v : BIGc;
                        res = (g == gcap) ? v : res;   // capture (always slow window)
                    }
                    // refill slot s from window q+1 (scalar base + constant r)
                    Dwin[s] = Dbat[sbN + r];
                    {
                        int d1 = (gN < 512) ? (gN + 1) : (1023 - gN);
                        sbN += d1 - ((gN >= 511) ? 1 : 0);
                        ++gN;
                    }
                    f4set(expv[s >> 2], s, v);
                    const float sh = dpp_shr1_f(v, BIGc);
                    nb2 = nb1;
                    nb1 = l0 ? f4c(rv[s >> 2], s) : sh;   // slot s -> nb1 for g+1
                    own = v;
                }
            };
            if (fastC) body(TrueC{}); else body(FalseC{});

            // ring export: 4x b128 from packed regs (lane 63 only)
            if (W < 7 && lane == 63) {
                float* re = &ring[W + 1][rbase];
                #pragma unroll
                for (int u = 0; u < 4; ++u)
                    reinterpret_cast<float4*>(re)[u] = expv[u];
            }
        } else if (W > 0 && q == q0 - 1) {
            // preload: ring slots 62/63 hold v(64W-1, 64W-2) and v(64W-1, 64W-1)
            nb1 = l0 ? ring[W][63] : nb1;
            nb2 = l0 ? ring[W][62] : nb2;
        }
        asm volatile("s_waitcnt lgkmcnt(0)" ::: "memory");  // ring writes visible
        __builtin_amdgcn_s_barrier();                       // no vmcnt drain
        asm volatile("" ::: "memory");
    }

    if (r == L - 1) out[b] = res * LN2;
}

// ---------------- Fallback (no workspace): fused on-the-fly D --------------------
__global__ __launch_bounds__(512)
void softdtw_fused(const float* __restrict__ X, const float* __restrict__ Y,
                   const int* __restrict__ lengths, float* __restrict__ out)
{
    const int b = blockIdx.x;
    const int t = threadIdx.x;
    const int i = t + 1;
    const int L = lengths[b];

    __shared__ float diag[3][Nc + 1];
    for (int c = t; c <= Nc; c += 512) {
        diag[0][c] = (c == 0) ? 0.f : BIGc;
        diag[1][c] = BIGc;
    }
    float xr[DIMc];
    const float* Xrow = X + ((size_t)b * Nc + t) * DIMc;
    #pragma unroll
    for (int d = 0; d < DIMc; d += 4) {
        float4 v = *reinterpret_cast<const float4*>(Xrow + d);
        xr[d] = v.x; xr[d+1] = v.y; xr[d+2] = v.z; xr[d+3] = v.w;
    }
    const float* Yb = Y + (size_t)b * Mc * DIMc;
    __syncthreads();

    float result = BIGc;
    int cur = 2, p1 = 1, p2 = 0;
    for (int k = 2; k <= Nc + Mc; ++k) {
        const int j = k - i;
        const bool valid = (j >= 1) && (j <= Mc) && (i <= L);
        float Dval = 0.f;
        if (valid) {
            const float* Yrow = Yb + (size_t)(j - 1) * DIMc;
            float s = 0.f;
            #pragma unroll
            for (int d = 0; d < DIMc; d += 4) {
                float4 v = *reinterpret_cast<const float4*>(Yrow + d);
                float d0 = xr[d] - v.x, d1 = xr[d+1] - v.y;
                float d2 = xr[d+2] - v.z, d3 = xr[d+3] - v.w;
                s = fmaf(d0,d0,s); s = fmaf(d1,d1,s); s = fmaf(d2,d2,s); s = fmaf(d3,d3,s);
            }
            Dval = s;
        }
        const float a2 = diag[p2][i-1], a1 = diag[p1][i-1], a0 = diag[p1][i];
        const float mn = fminf(a2, fminf(a1, a0));
        const float sm = mn - __logf(__expf(mn-a2) + __expf(mn-a1) + __expf(mn-a0));
        const float val = valid ? (Dval + sm) : BIGc;
        diag[cur][i] = val;
        if (t == 0) diag[cur][0] = BIGc;
        if (k == L + Mc && i == L) result = val;
        __syncthreads();
        const int tmp = p2; p2 = p1; p1 = cur; cur = tmp;
    }
    if (i == L) out[b] = result;
}

extern "C" void kernel_launch(void* const* d_in, const int* in_sizes, int n_in,
                              void* d_out, int out_size, void* d_ws, size_t ws_size,
                              hipStream_t stream) {
    const float* X = (const float*)d_in[0];
    const float* Y = (const float*)d_in[1];
    const int* lengths = (const int*)d_in[2];
    float* out = (float*)d_out;

    const size_t need = (size_t)Bc * CELLS * sizeof(unsigned short);  // 32 MiB
    if (ws_size >= need) {
        unsigned short* Dc = (unsigned short*)d_ws;
        compute_D_mfma<<<dim3(Bc, 16), 256, 0, stream>>>(X, Y, Dc);
        softdtw_sys16<<<Bc, 512, 0, stream>>>(Dc, lengths, out);
    } else {
        softdtw_fused<<<Bc, 512, 0, stream>>>(X, Y, lengths, out);
    }
}